// Round 10
// baseline (1388.508 us; speedup 1.0000x reference)
//
#include <hip/hip_runtime.h>
#include <cstddef>

#define HW 16384
#define WID 128

typedef __attribute__((ext_vector_type(8))) short short8;
typedef __attribute__((ext_vector_type(4))) float f32x4;

// async global->LDS, 4B per lane; LDS dest = wave-uniform base + lane*4
#define GLD4(g, l)                                                        \
    __builtin_amdgcn_global_load_lds(                                     \
        (const __attribute__((address_space(1))) unsigned int*)(g),       \
        (__attribute__((address_space(3))) unsigned int*)(l), 4, 0, 0)

__device__ __forceinline__ int wstart(int i) {
    // K=7, DIL=2, L=128: nh*d = 6
    if (i < 6) return i & 1;
    if (i >= 122) return 114 + (i & 1);
    return i - 6;
}
__device__ __forceinline__ int pbstart(int i) {
    if (i < 6) return 6 - (i >> 1);
    if (i >= 122) return (127 - i) >> 1;
    return 3;
}

__device__ __forceinline__ unsigned short bf16rne(float f) {
    unsigned u = __builtin_bit_cast(unsigned, f);
    u += 0x7FFFu + ((u >> 16) & 1u);
    return (unsigned short)(u >> 16);
}
__device__ __forceinline__ void bsplit(float f, unsigned short& h, unsigned short& l) {
    h = bf16rne(f);
    float hf = __builtin_bit_cast(float, ((unsigned)h) << 16);
    l = bf16rne(f - hf);
}

// ---------------- transpose + bf16 hi/lo split: [C][HW] fp32 -> [C/32][HW][32] ----------------
__global__ __launch_bounds__(256) void pack_t(const float* __restrict__ src, size_t bstr,
                                              unsigned short* __restrict__ dh,
                                              unsigned short* __restrict__ dl) {
    __shared__ float sm[32][260];
    const int p0 = blockIdx.x * 256, c32 = blockIdx.y, b = blockIdx.z;
    const float* s = src + (size_t)b * bstr + (size_t)(c32 * 32) * HW + p0;
    const int t = threadIdx.x;
    const int rr = t >> 3, f = t & 7;
#pragma unroll
    for (int u = 0; u < 8; u++) {
        float4 v = *(const float4*)(s + (size_t)rr * HW + (f + 8 * u) * 4);
        *(float4*)&sm[rr][(f + 8 * u) * 4] = v;
    }
    __syncthreads();
    size_t off = ((size_t)(b * 8 + c32) * HW + p0 + t) * 32;
#pragma unroll
    for (int w = 0; w < 4; w++) {
        short8 vh, vl;
#pragma unroll
        for (int e = 0; e < 8; e++) {
            unsigned short h, lo_;
            bsplit(sm[w * 8 + e][t], h, lo_);
            vh[e] = (short)h;
            vl[e] = (short)lo_;
        }
        *(short8*)&dh[off + w * 8] = vh;
        *(short8*)&dl[off + w * 8] = vl;
    }
}

// ---------------- split-bf16 MFMA GEMM ----------------
// QKV mode: writes q/k/v pair-interleaved [s][b][128cp][HW][2] + fused RoPE/scale.
// proj mode: writes channel-plane fp32 [b][256][HW] (d_out).
template <bool QKV>
__global__ __launch_bounds__(256, 2) void gemm_mfma(
    const float* __restrict__ Wm, const unsigned short* __restrict__ xh,
    const unsigned short* __restrict__ xl, const float* __restrict__ bias,
    const float* __restrict__ sinp, const float* __restrict__ cosp,
    float* __restrict__ Y, int NMT) {
    __shared__ unsigned short As_h[128][40], As_l[128][40];
    __shared__ unsigned short Bs_h[128][40], Bs_l[128][40];
    const int bid = blockIdx.x;
    const int xcd = bid & 7, r = bid >> 3;
    const int mt = r % NMT;
    const int q2 = r / NMT;
    const int nt = xcd * 16 + (q2 & 15);
    const int b = q2 >> 4;
    const int t = threadIdx.x;
    const int lane = t & 63, wid = t >> 6;
    const int wm = wid >> 1, wn = wid & 1;
    const int m0 = mt * 128;

    f32x4 acc[4][4];
#pragma unroll
    for (int i = 0; i < 4; i++)
#pragma unroll
        for (int j = 0; j < 4; j++) acc[i][j] = (f32x4){0.f, 0.f, 0.f, 0.f};

    const int sr = t >> 1, sh = t & 1;
    const float* arow = Wm + (size_t)(m0 + sr) * 256 + sh * 16;
    const unsigned short* bh_b = xh + ((size_t)(b * 8) * HW + (size_t)nt * 128 + sr) * 32 + sh * 16;
    const unsigned short* bl_b = xl + ((size_t)(b * 8) * HW + (size_t)nt * 128 + sr) * 32 + sh * 16;

    for (int ks = 0; ks < 8; ks++) {
        {
            const float* ap = arow + ks * 32;
#pragma unroll
            for (int g = 0; g < 2; g++) {
                float4 f0 = *(const float4*)(ap + g * 8);
                float4 f1 = *(const float4*)(ap + g * 8 + 4);
                float ff[8] = {f0.x, f0.y, f0.z, f0.w, f1.x, f1.y, f1.z, f1.w};
                short8 vh, vl;
#pragma unroll
                for (int e = 0; e < 8; e++) {
                    unsigned short h, lo_;
                    bsplit(ff[e], h, lo_);
                    vh[e] = (short)h;
                    vl[e] = (short)lo_;
                }
                *(short8*)&As_h[sr][sh * 16 + g * 8] = vh;
                *(short8*)&As_l[sr][sh * 16 + g * 8] = vl;
            }
        }
        {
            const unsigned short* bp = bh_b + (size_t)ks * HW * 32;
            const unsigned short* lp = bl_b + (size_t)ks * HW * 32;
            *(short8*)&Bs_h[sr][sh * 16] = *(const short8*)(bp);
            *(short8*)&Bs_h[sr][sh * 16 + 8] = *(const short8*)(bp + 8);
            *(short8*)&Bs_l[sr][sh * 16] = *(const short8*)(lp);
            *(short8*)&Bs_l[sr][sh * 16 + 8] = *(const short8*)(lp + 8);
        }
        __syncthreads();
        const int k8 = (lane >> 4) * 8;
        short8 a_h[4], a_l[4];
#pragma unroll
        for (int mi = 0; mi < 4; mi++) {
            int am = wm * 64 + mi * 16 + (lane & 15);
            a_h[mi] = *(const short8*)&As_h[am][k8];
            a_l[mi] = *(const short8*)&As_l[am][k8];
        }
#pragma unroll
        for (int ni = 0; ni < 4; ni++) {
            int bn = wn * 64 + ni * 16 + (lane & 15);
            short8 b_h = *(const short8*)&Bs_h[bn][k8];
            short8 b_l = *(const short8*)&Bs_l[bn][k8];
#pragma unroll
            for (int mi = 0; mi < 4; mi++) {
                acc[mi][ni] = __builtin_amdgcn_mfma_f32_16x16x32_bf16(a_h[mi], b_h, acc[mi][ni], 0, 0, 0);
                acc[mi][ni] = __builtin_amdgcn_mfma_f32_16x16x32_bf16(a_h[mi], b_l, acc[mi][ni], 0, 0, 0);
                acc[mi][ni] = __builtin_amdgcn_mfma_f32_16x16x32_bf16(a_l[mi], b_h, acc[mi][ni], 0, 0, 0);
            }
        }
        __syncthreads();
    }

    const int col = lane & 15, rq = (lane >> 4) * 4;
    const int s = QKV ? (mt >> 1) : 3;
#pragma unroll
    for (int mi = 0; mi < 4; mi++) {
        int mrow = m0 + wm * 64 + mi * 16 + rq;
        float b0 = bias[mrow], b1 = bias[mrow + 1], b2 = bias[mrow + 2], b3 = bias[mrow + 3];
#pragma unroll
        for (int ni = 0; ni < 4; ni++) {
            int p = nt * 128 + wn * 64 + ni * 16 + col;
            float v0 = acc[mi][ni][0] + b0, v1 = acc[mi][ni][1] + b1;
            float v2 = acc[mi][ni][2] + b2, v3 = acc[mi][ni][3] + b3;
            if (QKV) {
                if (s < 2) {
                    int d0 = (mi & 1) * 16 + rq;
                    const float* cp = cosp + (size_t)p * 32 + d0;
                    const float* sp = sinp + (size_t)p * 32 + d0;
                    float c0 = cp[0], c1 = cp[1], c2 = cp[2], c3 = cp[3];
                    float s0 = sp[0], s1 = sp[1], s2 = sp[2], s3 = sp[3];
                    float n0 = v0 * c0 - v1 * s0, n1 = v1 * c1 + v0 * s1;
                    float n2 = v2 * c2 - v3 * s2, n3 = v3 * c3 + v2 * s3;
                    if (s == 0) {
                        const float sc = 0.17677669529663687f;
                        n0 *= sc; n1 *= sc; n2 *= sc; n3 *= sc;
                    }
                    v0 = n0; v1 = n1; v2 = n2; v3 = n3;
                }
                // pair-interleaved store: [s][b][128cp][HW][2]
                int cloc = mrow & 255;  // 0..255, rq even
                float* dst = Y + (size_t)s * 16777216ull +
                             ((size_t)(b * 128 + (cloc >> 1))) * 32768ull + (size_t)p * 2;
                float2 w0 = {v0, v1}, w1 = {v2, v3};
                *(float2*)dst = w0;
                *(float2*)(dst + 32768) = w1;
            } else {
                float* yp = Y + ((size_t)b * 256 + mrow) * HW + p;
                yp[0] = v0;
                yp[HW] = v1;
                yp[2 * HW] = v2;
                yp[3 * HW] = v3;
            }
        }
    }
}

// ---------------- Neighborhood attention + fused LePE, v5 (channel-pair float2) ----
// 512 thr = 4 rows x 128 cols. Window 16 rows x 128 cols x 2 channels = 16 KB,
// double-buffered; DMA + counted vmcnt pipeline (T3/T4); 16 pair-iterations.
// Each LDS tap is a float2 serving 2 channels -> ~2x fewer LDS-read instructions.
#define CBUF 4096  // 16*128*2 floats
__global__ __launch_bounds__(512, 8) void attn_k(const float* __restrict__ qkv2,
                                                 const float* __restrict__ rpb,
                                                 const float* __restrict__ wl,
                                                 const float* __restrict__ bl,
                                                 float* __restrict__ outp) {
    __shared__ float sm[2 * CBUF];
    const int t = threadIdx.x;
    const int ty = t >> 7;          // 0..3
    const int j = t & 127;
    const int thi = t >> 8;         // 0..1 (staging row parity)
    const int tcol = t & 255;       // staging col-dword
    const int bid = blockIdx.x;     // 1024 = 32 it x 8 n x 4 b
    const int it = bid & 31, nb = bid >> 5;
    const int n = nb & 7, b = nb >> 3;
    const int i0 = it * 4, i = i0 + ty;
    const int r0 = wstart(i0);      // window rows r0..r0+15
    const int wbase = (t >> 6) * 64;  // wave-uniform LDS lane base

    const int pb = b * 128 + n * 16;  // global pair base for this (b, head)
    const float* q2 = qkv2;
    const float* k2 = qkv2 + 16777216ull;
    const float* v2 = qkv2 + 33554432ull;
    const int p = i * WID + j;

    const int hs = wstart(i), ws_ = wstart(j);
    const int ph = pbstart(i), pw = pbstart(j);

    float sc[49];
    const float* rp = rpb + n * 169;
#pragma unroll
    for (int ki = 0; ki < 7; ki++)
#pragma unroll
        for (int kj = 0; kj < 7; kj++)
            sc[ki * 7 + kj] = rp[(ph + ki) * 13 + (pw + kj)];

    const int lrbase = hs - r0;          // 0..3
    const int abase = lrbase * 256 + ws_ * 2;  // float index of tap (ki=0,kj=0)

    // ---- prologue: DMA k-pair 0 window + load q-pair 0 ----
    {
        const float* kpl = k2 + (size_t)pb * 32768ull;
#pragma unroll
        for (int u = 0; u < 8; u++) {
            int row = r0 + 2 * u + thi; if (row > 127) row = 127;
            GLD4(kpl + row * 256 + tcol, &sm[u * 512 + wbase]);
        }
    }
    float2 qv = *(const float2*)(q2 + (size_t)pb * 32768ull + (size_t)p * 2);
    float2 qn;

    // ---- QK^T: 16 pair iterations ----
    for (int cp = 0; cp < 16; cp++) {
        float* bc = sm + (cp & 1) * CBUF;
        float* bnx = sm + ((cp + 1) & 1) * CBUF;
        if (cp < 15) {
            const float* kpl = k2 + (size_t)(pb + cp + 1) * 32768ull;
#pragma unroll
            for (int u = 0; u < 8; u++) {
                int row = r0 + 2 * u + thi; if (row > 127) row = 127;
                GLD4(kpl + row * 256 + tcol, &bnx[u * 512 + wbase]);
            }
            qn = *(const float2*)(q2 + (size_t)(pb + cp + 1) * 32768ull + (size_t)p * 2);
            asm volatile("s_waitcnt vmcnt(9)" ::: "memory");
        } else {
            const float* vpl = v2 + (size_t)pb * 32768ull;
#pragma unroll
            for (int u = 0; u < 8; u++) {
                int row = r0 + 2 * u + thi; if (row > 127) row = 127;
                GLD4(vpl + row * 256 + tcol, &bnx[u * 512 + wbase]);
            }
            asm volatile("s_waitcnt vmcnt(8)" ::: "memory");
        }
        __builtin_amdgcn_s_barrier();
        __builtin_amdgcn_s_setprio(1);
        const float* ab = bc + abase;
#pragma unroll
        for (int ki = 0; ki < 7; ki++) {
            const float* kib = ab + ki * 512;
#pragma unroll
            for (int kj = 0; kj < 7; kj++) {
                float2 tp = *(const float2*)(kib + kj * 4);
                sc[ki * 7 + kj] = fmaf(qv.x, tp.x, sc[ki * 7 + kj]);
                sc[ki * 7 + kj] = fmaf(qv.y, tp.y, sc[ki * 7 + kj]);
            }
        }
        __builtin_amdgcn_s_setprio(0);
        qv = qn;
        __builtin_amdgcn_s_barrier();
    }

    // ---- softmax over 49 (v pair 0 in flight) ----
    float mx = sc[0];
#pragma unroll
    for (int u = 1; u < 49; u++) mx = fmaxf(mx, sc[u]);
    float sum = 0.0f;
#pragma unroll
    for (int u = 0; u < 49; u++) {
        sc[u] = __expf(sc[u] - mx);
        sum += sc[u];
    }
    float inv = 1.0f / sum;
#pragma unroll
    for (int u = 0; u < 49; u++) sc[u] *= inv;

    // ---- PV + LePE: 16 pair iterations ----
    float* ob = outp + ((size_t)(b * 256 + n * 32) * HW) + p;
    const float* wbaseL = wl + (size_t)(n * 32) * 25;
    const float* blb = bl + n * 32;
    for (int cp = 0; cp < 16; cp++) {
        float* bc = sm + (cp & 1) * CBUF;
        float* bnx = sm + ((cp + 1) & 1) * CBUF;
        if (cp < 15) {
            const float* vpl = v2 + (size_t)(pb + cp + 1) * 32768ull;
#pragma unroll
            for (int u = 0; u < 8; u++) {
                int row = r0 + 2 * u + thi; if (row > 127) row = 127;
                GLD4(vpl + row * 256 + tcol, &bnx[u * 512 + wbase]);
            }
            asm volatile("s_waitcnt vmcnt(8)" ::: "memory");
        } else {
            asm volatile("s_waitcnt vmcnt(0)" ::: "memory");
        }
        __builtin_amdgcn_s_barrier();
        __builtin_amdgcn_s_setprio(1);
        const float* ab = bc + abase;
        float oc0 = 0.0f, oc1 = 0.0f;
#pragma unroll
        for (int ki = 0; ki < 7; ki++) {
            const float* kib = ab + ki * 512;
#pragma unroll
            for (int kj = 0; kj < 7; kj++) {
                float2 tp = *(const float2*)(kib + kj * 4);
                float w = sc[ki * 7 + kj];
                oc0 = fmaf(w, tp.x, oc0);
                oc1 = fmaf(w, tp.y, oc1);
            }
        }
        // LePE 5x5 for channels 2cp, 2cp+1 from the same staged window
        const int ch = 2 * cp;
        const float* w0 = wbaseL + ch * 25;
        const float* w1 = w0 + 25;
        float la0 = blb[ch], la1 = blb[ch + 1];
#pragma unroll
        for (int di = 0; di < 5; di++) {
            int ii = i + di - 2;
            if ((unsigned)ii < 128u) {
                const float* srow = bc + (ii - r0) * 256;
#pragma unroll
                for (int dj = 0; dj < 5; dj++) {
                    int jj = j + dj - 2;
                    if ((unsigned)jj < 128u) {
                        float2 tp = *(const float2*)(srow + jj * 2);
                        la0 = fmaf(w0[di * 5 + dj], tp.x, la0);
                        la1 = fmaf(w1[di * 5 + dj], tp.y, la1);
                    }
                }
            }
        }
        __builtin_amdgcn_s_setprio(0);
        ob[(size_t)ch * HW] = oc0 + la0;
        ob[(size_t)(ch + 1) * HW] = oc1 + la1;
        __builtin_amdgcn_s_barrier();
    }
}

extern "C" void kernel_launch(void* const* d_in, const int* in_sizes, int n_in,
                              void* d_out, int out_size, void* d_ws, size_t ws_size,
                              hipStream_t stream) {
    const float* x = (const float*)d_in[0];
    const float* sinp = (const float*)d_in[1];
    const float* cosp = (const float*)d_in[2];
    const float* w_qkv = (const float*)d_in[3];
    const float* b_qkv = (const float*)d_in[4];
    const float* w_lepe = (const float*)d_in[5];
    const float* b_lepe = (const float*)d_in[6];
    const float* w_proj = (const float*)d_in[7];
    const float* b_proj = (const float*)d_in[8];
    const float* rpb = (const float*)d_in[9];
    float* out = (float*)d_out;

    // ws layout (268,435,456 B exactly):
    //   phase 1: xph_in/xpl_in at [201.3MB, 268.4MB) (written by pack#1, read by QKV gemm)
    //   phase 2: q2k2v2 pair-interleaved at [0, 201.3MB) (QKV gemm out, attn in)
    //   phase 3: attn-out fp32 [b][256][HW] at [201.3MB, 268.4MB) (over dead xp*_in)
    //   phase 4: xph2/xpl2 at [0, 67.1MB) (pack#2 out over dead q2, proj in)
    float* wsf = (float*)d_ws;
    float* qkv2 = wsf;                           // 50,331,648 floats
    float* attno = wsf + 50331648ull;            // 16,777,216 floats
    unsigned short* xph_in = (unsigned short*)attno;
    unsigned short* xpl_in = xph_in + 16777216ull;
    unsigned short* xph2 = (unsigned short*)wsf;
    unsigned short* xpl2 = xph2 + 16777216ull;

    // 1) split/transpose x -> high region
    pack_t<<<dim3(64, 8, 4), 256, 0, stream>>>(x, (size_t)256 * HW, xph_in, xpl_in);
    // 2) QKV projection (MFMA) + fused bias/RoPE/scale -> pair-interleaved q2k2v2
    gemm_mfma<true><<<dim3(3072), 256, 0, stream>>>(w_qkv, xph_in, xpl_in, b_qkv, sinp, cosp,
                                                    qkv2, 6);
    // 3) neighborhood attention + fused LePE -> attno (channel-plane, high region)
    attn_k<<<dim3(1024), 512, 0, stream>>>(qkv2, rpb, w_lepe, b_lepe, attno);
    // 4) split/transpose attn+lepe output -> low region
    pack_t<<<dim3(64, 8, 4), 256, 0, stream>>>(attno, (size_t)256 * HW, xph2, xpl2);
    // 5) output projection (MFMA) -> d_out
    gemm_mfma<false><<<dim3(1024), 256, 0, stream>>>(w_proj, xph2, xpl2, b_proj, nullptr, nullptr,
                                                     out, 2);
}

// Round 11
// 406.661 us; speedup vs baseline: 3.4144x; 3.4144x over previous
//
#include <hip/hip_runtime.h>
#include <cstddef>

#define HW 16384
#define WID 128

typedef __attribute__((ext_vector_type(8))) short short8;
typedef __attribute__((ext_vector_type(4))) float f32x4;

// async global->LDS, 4B per lane; LDS dest = wave-uniform base + lane*4
#define GLD4(g, l)                                                        \
    __builtin_amdgcn_global_load_lds(                                     \
        (const __attribute__((address_space(1))) unsigned int*)(g),       \
        (__attribute__((address_space(3))) unsigned int*)(l), 4, 0, 0)

__device__ __forceinline__ int wstart(int i) {
    // K=7, DIL=2, L=128: nh*d = 6
    if (i < 6) return i & 1;
    if (i >= 122) return 114 + (i & 1);
    return i - 6;
}
__device__ __forceinline__ int pbstart(int i) {
    if (i < 6) return 6 - (i >> 1);
    if (i >= 122) return (127 - i) >> 1;
    return 3;
}

__device__ __forceinline__ unsigned short bf16rne(float f) {
    unsigned u = __builtin_bit_cast(unsigned, f);
    u += 0x7FFFu + ((u >> 16) & 1u);
    return (unsigned short)(u >> 16);
}
__device__ __forceinline__ void bsplit(float f, unsigned short& h, unsigned short& l) {
    h = bf16rne(f);
    float hf = __builtin_bit_cast(float, ((unsigned)h) << 16);
    l = bf16rne(f - hf);
}

// ---------------- transpose + bf16 hi/lo split: [C][HW] fp32 -> [C/32][HW][32] ----------------
__global__ __launch_bounds__(256) void pack_t(const float* __restrict__ src, size_t bstr,
                                              unsigned short* __restrict__ dh,
                                              unsigned short* __restrict__ dl) {
    __shared__ float sm[32][260];
    const int p0 = blockIdx.x * 256, c32 = blockIdx.y, b = blockIdx.z;
    const float* s = src + (size_t)b * bstr + (size_t)(c32 * 32) * HW + p0;
    const int t = threadIdx.x;
    const int rr = t >> 3, f = t & 7;
#pragma unroll
    for (int u = 0; u < 8; u++) {
        float4 v = *(const float4*)(s + (size_t)rr * HW + (f + 8 * u) * 4);
        *(float4*)&sm[rr][(f + 8 * u) * 4] = v;
    }
    __syncthreads();
    size_t off = ((size_t)(b * 8 + c32) * HW + p0 + t) * 32;
#pragma unroll
    for (int w = 0; w < 4; w++) {
        short8 vh, vl;
#pragma unroll
        for (int e = 0; e < 8; e++) {
            unsigned short h, lo_;
            bsplit(sm[w * 8 + e][t], h, lo_);
            vh[e] = (short)h;
            vl[e] = (short)lo_;
        }
        *(short8*)&dh[off + w * 8] = vh;
        *(short8*)&dl[off + w * 8] = vl;
    }
}

// ---------------- split-bf16 MFMA GEMM (round-6/9 version) ----------------
template <bool QKV>
__global__ __launch_bounds__(256, 2) void gemm_mfma(
    const float* __restrict__ Wm, const unsigned short* __restrict__ xh,
    const unsigned short* __restrict__ xl, const float* __restrict__ bias,
    const float* __restrict__ sinp, const float* __restrict__ cosp,
    float* __restrict__ Y, int NMT, int MT) {
    __shared__ unsigned short As_h[128][40], As_l[128][40];
    __shared__ unsigned short Bs_h[128][40], Bs_l[128][40];
    const int bid = blockIdx.x;
    const int xcd = bid & 7, r = bid >> 3;
    const int mt = r % NMT;
    const int q2 = r / NMT;
    const int nt = xcd * 16 + (q2 & 15);
    const int b = q2 >> 4;
    const int t = threadIdx.x;
    const int lane = t & 63, wid = t >> 6;
    const int wm = wid >> 1, wn = wid & 1;
    const int m0 = mt * 128;

    f32x4 acc[4][4];
#pragma unroll
    for (int i = 0; i < 4; i++)
#pragma unroll
        for (int j = 0; j < 4; j++) acc[i][j] = (f32x4){0.f, 0.f, 0.f, 0.f};

    const int sr = t >> 1, sh = t & 1;
    const float* arow = Wm + (size_t)(m0 + sr) * 256 + sh * 16;
    const unsigned short* bh_b = xh + ((size_t)(b * 8) * HW + (size_t)nt * 128 + sr) * 32 + sh * 16;
    const unsigned short* bl_b = xl + ((size_t)(b * 8) * HW + (size_t)nt * 128 + sr) * 32 + sh * 16;

    for (int ks = 0; ks < 8; ks++) {
        {
            const float* ap = arow + ks * 32;
#pragma unroll
            for (int g = 0; g < 2; g++) {
                float4 f0 = *(const float4*)(ap + g * 8);
                float4 f1 = *(const float4*)(ap + g * 8 + 4);
                float ff[8] = {f0.x, f0.y, f0.z, f0.w, f1.x, f1.y, f1.z, f1.w};
                short8 vh, vl;
#pragma unroll
                for (int e = 0; e < 8; e++) {
                    unsigned short h, lo_;
                    bsplit(ff[e], h, lo_);
                    vh[e] = (short)h;
                    vl[e] = (short)lo_;
                }
                *(short8*)&As_h[sr][sh * 16 + g * 8] = vh;
                *(short8*)&As_l[sr][sh * 16 + g * 8] = vl;
            }
        }
        {
            const unsigned short* bp = bh_b + (size_t)ks * HW * 32;
            const unsigned short* lp = bl_b + (size_t)ks * HW * 32;
            *(short8*)&Bs_h[sr][sh * 16] = *(const short8*)(bp);
            *(short8*)&Bs_h[sr][sh * 16 + 8] = *(const short8*)(bp + 8);
            *(short8*)&Bs_l[sr][sh * 16] = *(const short8*)(lp);
            *(short8*)&Bs_l[sr][sh * 16 + 8] = *(const short8*)(lp + 8);
        }
        __syncthreads();
        const int k8 = (lane >> 4) * 8;
        short8 a_h[4], a_l[4];
#pragma unroll
        for (int mi = 0; mi < 4; mi++) {
            int am = wm * 64 + mi * 16 + (lane & 15);
            a_h[mi] = *(const short8*)&As_h[am][k8];
            a_l[mi] = *(const short8*)&As_l[am][k8];
        }
#pragma unroll
        for (int ni = 0; ni < 4; ni++) {
            int bn = wn * 64 + ni * 16 + (lane & 15);
            short8 b_h = *(const short8*)&Bs_h[bn][k8];
            short8 b_l = *(const short8*)&Bs_l[bn][k8];
#pragma unroll
            for (int mi = 0; mi < 4; mi++) {
                acc[mi][ni] = __builtin_amdgcn_mfma_f32_16x16x32_bf16(a_h[mi], b_h, acc[mi][ni], 0, 0, 0);
                acc[mi][ni] = __builtin_amdgcn_mfma_f32_16x16x32_bf16(a_h[mi], b_l, acc[mi][ni], 0, 0, 0);
                acc[mi][ni] = __builtin_amdgcn_mfma_f32_16x16x32_bf16(a_l[mi], b_h, acc[mi][ni], 0, 0, 0);
            }
        }
        __syncthreads();
    }

    const int col = lane & 15, rq = (lane >> 4) * 4;
    const int s = QKV ? (mt >> 1) : 3;
#pragma unroll
    for (int mi = 0; mi < 4; mi++) {
        int mrow = m0 + wm * 64 + mi * 16 + rq;
        float b0 = bias[mrow], b1 = bias[mrow + 1], b2 = bias[mrow + 2], b3 = bias[mrow + 3];
#pragma unroll
        for (int ni = 0; ni < 4; ni++) {
            int p = nt * 128 + wn * 64 + ni * 16 + col;
            float v0 = acc[mi][ni][0] + b0, v1 = acc[mi][ni][1] + b1;
            float v2 = acc[mi][ni][2] + b2, v3 = acc[mi][ni][3] + b3;
            if (QKV && s < 2) {
                int d0 = (mi & 1) * 16 + rq;
                const float* cp = cosp + (size_t)p * 32 + d0;
                const float* sp = sinp + (size_t)p * 32 + d0;
                float c0 = cp[0], c1 = cp[1], c2 = cp[2], c3 = cp[3];
                float s0 = sp[0], s1 = sp[1], s2 = sp[2], s3 = sp[3];
                float n0 = v0 * c0 - v1 * s0, n1 = v1 * c1 + v0 * s1;
                float n2 = v2 * c2 - v3 * s2, n3 = v3 * c3 + v2 * s3;
                if (s == 0) {
                    const float sc = 0.17677669529663687f;
                    n0 *= sc; n1 *= sc; n2 *= sc; n3 *= sc;
                }
                v0 = n0; v1 = n1; v2 = n2; v3 = n3;
            }
            float* yp = Y + ((size_t)b * MT + mrow) * HW + p;
            yp[0] = v0;
            yp[HW] = v1;
            yp[2 * HW] = v2;
            yp[3 * HW] = v3;
        }
    }
}

// ---------------- Neighborhood attention + fused LePE, v6 ----------------
// Round-9 structure (256 thr = 2 rows x 128 cols, channel-plane, DMA + counted
// vmcnt) with TWO channels staged per phase (halves barriers/waits) and an
// XCD-aware i-tile swizzle (each XCD owns 16 contiguous pixel rows per (b,n)
// -> window halos and re-reads are XCD-local L2 hits).
#define CW 2048    // per-channel slot: 14x128 window (1792) + q 2x128 (256)
#define PBUF 4096  // 2 channels per phase buffer
__global__ __launch_bounds__(256) void attn_k(const float* __restrict__ qkv,
                                              const float* __restrict__ rpb,
                                              const float* __restrict__ wl,
                                              const float* __restrict__ bl,
                                              float* __restrict__ out) {
    __shared__ float sm[2 * PBUF];
    const int t = threadIdx.x;
    const int ty = t >> 7;
    const int j = t & 127;
    const int bx = blockIdx.x;
    const int ip = ((bx & 7) << 3) | (bx >> 3);  // XCD bx&7 owns 8 consecutive i-pairs
    const int i0 = ip * 2;
    const int i = i0 + ty;
    const int n = blockIdx.y, b = blockIdx.z;
    const int r0 = wstart(i0);      // window rows r0..r0+13 (always <= 127)
    const int w64 = (t >> 6) * 64;  // wave-uniform LDS lane base

    const float* qb = qkv + ((size_t)b * 768 + n * 32) * HW;
    const float* kb = qb + (size_t)256 * HW;
    const float* vb = qb + (size_t)512 * HW;
    const int p = i * WID + j;
    const float* qrow = qb + i0 * WID;  // + c*HW + t
    const float* krow = kb + r0 * WID;
    const float* vrow = vb + r0 * WID;

    const int hs = wstart(i), ws_ = wstart(j);
    const int ph = pbstart(i), pw = pbstart(j);

    float sc[49];
    const float* rp = rpb + n * 169;
#pragma unroll
    for (int ki = 0; ki < 7; ki++)
#pragma unroll
        for (int kj = 0; kj < 7; kj++)
            sc[ki * 7 + kj] = rp[(ph + ki) * 13 + (pw + kj)];

    const int aoff = (hs - r0) * WID + ws_;  // attn tap base within a window

    // ---- prologue: stage channels 0,1 (k windows + q rows) into buf0 ----
#pragma unroll
    for (int s = 0; s < 2; s++) {
        const float* kp = krow + (size_t)s * HW;
#pragma unroll
        for (int u = 0; u < 7; u++) GLD4(kp + u * 256 + t, &sm[s * CW + u * 256 + w64]);
        GLD4(qrow + (size_t)s * HW + t, &sm[s * CW + 1792 + w64]);
    }

    // ---- QK^T: 16 two-channel phases ----
    for (int cp = 0; cp < 16; cp++) {
        float* bc = sm + (cp & 1) * PBUF;
        float* bnx = sm + ((cp + 1) & 1) * PBUF;
        if (cp < 15) {
#pragma unroll
            for (int s = 0; s < 2; s++) {
                const int c = 2 * (cp + 1) + s;
                const float* kp = krow + (size_t)c * HW;
#pragma unroll
                for (int u = 0; u < 7; u++) GLD4(kp + u * 256 + t, &bnx[s * CW + u * 256 + w64]);
                GLD4(qrow + (size_t)c * HW + t, &bnx[s * CW + 1792 + w64]);
            }
            asm volatile("s_waitcnt vmcnt(16)" ::: "memory");
        } else {
            // stage v channels 0,1 (no q) so they fly during softmax
#pragma unroll
            for (int s = 0; s < 2; s++) {
                const float* vp = vrow + (size_t)s * HW;
#pragma unroll
                for (int u = 0; u < 7; u++) GLD4(vp + u * 256 + t, &bnx[s * CW + u * 256 + w64]);
            }
            asm volatile("s_waitcnt vmcnt(14)" ::: "memory");
        }
        __builtin_amdgcn_s_barrier();
        __builtin_amdgcn_s_setprio(1);
#pragma unroll
        for (int s = 0; s < 2; s++) {
            const float* bs = bc + s * CW;
            float qc = bs[1792 + t];
            const float* smb = bs + aoff;
#pragma unroll
            for (int ki = 0; ki < 7; ki++) {
                const float* kib = smb + ki * 256;
#pragma unroll
                for (int kj = 0; kj < 7; kj++)
                    sc[ki * 7 + kj] = fmaf(qc, kib[kj * 2], sc[ki * 7 + kj]);
            }
        }
        __builtin_amdgcn_s_setprio(0);
        __builtin_amdgcn_s_barrier();
    }

    // ---- softmax over 49 (v channels 0,1 in flight) ----
    float mx = sc[0];
#pragma unroll
    for (int u = 1; u < 49; u++) mx = fmaxf(mx, sc[u]);
    float sum = 0.0f;
#pragma unroll
    for (int u = 0; u < 49; u++) {
        sc[u] = __expf(sc[u] - mx);
        sum += sc[u];
    }
    float inv = 1.0f / sum;
#pragma unroll
    for (int u = 0; u < 49; u++) sc[u] *= inv;

    // ---- PV + LePE: 16 two-channel phases ----
    float* ob = out + ((size_t)b * 768 + n * 32) * HW + p;
    const float* wbase = wl + (size_t)(n * 32) * 25;
    const float* blb = bl + n * 32;
    for (int cp = 0; cp < 16; cp++) {
        float* bc = sm + (cp & 1) * PBUF;
        float* bnx = sm + ((cp + 1) & 1) * PBUF;
        if (cp < 15) {
#pragma unroll
            for (int s = 0; s < 2; s++) {
                const int c = 2 * (cp + 1) + s;
                const float* vp = vrow + (size_t)c * HW;
#pragma unroll
                for (int u = 0; u < 7; u++) GLD4(vp + u * 256 + t, &bnx[s * CW + u * 256 + w64]);
            }
            asm volatile("s_waitcnt vmcnt(14)" ::: "memory");
        } else {
            asm volatile("s_waitcnt vmcnt(0)" ::: "memory");
        }
        __builtin_amdgcn_s_barrier();
        __builtin_amdgcn_s_setprio(1);
#pragma unroll
        for (int s = 0; s < 2; s++) {
            const int ch = 2 * cp + s;
            const float* bs = bc + s * CW;
            const float* smb = bs + aoff;
            float oc = 0.0f;
#pragma unroll
            for (int ki = 0; ki < 7; ki++) {
                const float* kib = smb + ki * 256;
#pragma unroll
                for (int kj = 0; kj < 7; kj++)
                    oc = fmaf(sc[ki * 7 + kj], kib[kj * 2], oc);
            }
            // LePE 5x5 depthwise from the same staged window
            const float* wrow = wbase + ch * 25;
            float lac = blb[ch];
#pragma unroll
            for (int di = 0; di < 5; di++) {
                int ii = i + di - 2;
                if ((unsigned)ii < 128u) {
                    const float* srow = bs + (ii - r0) * WID;
                    const float* wr = wrow + di * 5;
#pragma unroll
                    for (int dj = 0; dj < 5; dj++) {
                        int jj = j + dj - 2;
                        if ((unsigned)jj < 128u)
                            lac = fmaf(wr[dj], srow[jj], lac);
                    }
                }
            }
            ob[(size_t)ch * HW] = oc + lac;
        }
        __builtin_amdgcn_s_setprio(0);
        __builtin_amdgcn_s_barrier();
    }
}

extern "C" void kernel_launch(void* const* d_in, const int* in_sizes, int n_in,
                              void* d_out, int out_size, void* d_ws, size_t ws_size,
                              hipStream_t stream) {
    const float* x = (const float*)d_in[0];
    const float* sinp = (const float*)d_in[1];
    const float* cosp = (const float*)d_in[2];
    const float* w_qkv = (const float*)d_in[3];
    const float* b_qkv = (const float*)d_in[4];
    const float* w_lepe = (const float*)d_in[5];
    const float* b_lepe = (const float*)d_in[6];
    const float* w_proj = (const float*)d_in[7];
    const float* b_proj = (const float*)d_in[8];
    const float* rpb = (const float*)d_in[9];
    float* out = (float*)d_out;

    // ws layout (256 MiB exactly, round-9 proven):
    //   [0, 32 MiB)    xph: bf16-hi packed transposed operand [b][8][HW][32]
    //   [32, 64 MiB)   xpl: bf16-lo
    //   [64, 256 MiB)  qkvb: fp32 [b][768][HW]; q-region doubles as attn+lepe output
    unsigned short* xph = (unsigned short*)d_ws;
    unsigned short* xpl = xph + 16777216ull;
    float* qkvb = (float*)(xph + 33554432ull);

    // 1) split/transpose x
    pack_t<<<dim3(64, 8, 4), 256, 0, stream>>>(x, (size_t)256 * HW, xph, xpl);
    // 2) QKV projection (MFMA) + fused bias/RoPE/scale -> qkvb
    gemm_mfma<true><<<dim3(3072), 256, 0, stream>>>(w_qkv, xph, xpl, b_qkv, sinp, cosp,
                                                    qkvb, 6, 768);
    // 3) neighborhood attention + fused LePE -> q-region of qkvb
    attn_k<<<dim3(64, 8, 4), 256, 0, stream>>>(qkvb, rpb, w_lepe, b_lepe, qkvb);
    // 4) split/transpose attn+lepe output
    pack_t<<<dim3(64, 8, 4), 256, 0, stream>>>(qkvb, (size_t)768 * HW, xph, xpl);
    // 5) output projection (MFMA) -> d_out
    gemm_mfma<false><<<dim3(1024), 256, 0, stream>>>(w_proj, xph, xpl, b_proj, nullptr, nullptr,
                                                     out, 2, 256);
}